// Round 1
// baseline (4218.238 us; speedup 1.0000x reference)
//
#include <hip/hip_runtime.h>
#include <stdint.h>

#define D 512
#define GD 2048
#define RNUM 8
#define TSTEPS 128

typedef __attribute__((ext_vector_type(8))) short s16x8;
typedef __attribute__((ext_vector_type(4))) float f32x4_t;

#define MFMA16(a, b, c) __builtin_amdgcn_mfma_f32_16x16x32_bf16((a), (b), (c), 0, 0, 0)

__device__ __forceinline__ unsigned short f2bf(float f) {
    union { float f; unsigned int u; } v; v.f = f;
    unsigned int r = (v.u + 0x7FFFu + ((v.u >> 16) & 1u)) >> 16;
    return (unsigned short)r;
}

// ---------------- precompute ----------------

__global__ void k_convert_wcat(const float* __restrict__ W_ih, const float* __restrict__ W_hh,
                               const float* __restrict__ b_ih, const float* __restrict__ b_hh,
                               unsigned short* __restrict__ wcat, float* __restrict__ bias) {
    int col = blockIdx.x;  // 0..2047
    for (int k = threadIdx.x; k < D; k += 256) {
        wcat[(long)col * 1024 + k]       = f2bf(W_ih[(long)col * D + k]);
        wcat[(long)col * 1024 + 512 + k] = f2bf(W_hh[(long)col * D + k]);
    }
    if (threadIdx.x == 0) bias[col] = b_ih[col] + b_hh[col];
}

__global__ void k_convert_wrel(const float* __restrict__ W_rel, unsigned short* __restrict__ wrel, int n) {
    int i = blockIdx.x * 256 + threadIdx.x;
    if (i < n) wrel[i] = f2bf(W_rel[i]);
}

__global__ void k_count(const int* __restrict__ rels, int n, int* __restrict__ cnt) {
    __shared__ int lc[RNUM];
    if (threadIdx.x < RNUM) lc[threadIdx.x] = 0;
    __syncthreads();
    int i = blockIdx.x * 256 + threadIdx.x;
    if (i < n) atomicAdd(&lc[rels[i]], 1);
    __syncthreads();
    if (threadIdx.x < RNUM) atomicAdd(&cnt[threadIdx.x], lc[threadIdx.x]);
}

__global__ void k_offsets(const int* __restrict__ cnt, int* __restrict__ roff, int* __restrict__ cur) {
    int acc = 0;
    for (int r = 0; r < RNUM; ++r) { roff[r] = acc; cur[r] = acc; acc += cnt[r]; }
    roff[RNUM] = acc;
}

__global__ void k_scatter(const int* __restrict__ rels, int n, int* __restrict__ cur, int* __restrict__ perm) {
    __shared__ int lc[RNUM];
    __shared__ int lbase[RNUM];
    if (threadIdx.x < RNUM) lc[threadIdx.x] = 0;
    __syncthreads();
    int i = blockIdx.x * 256 + threadIdx.x;
    int r = 0, lpos = 0;
    bool ok = (i < n);
    if (ok) { r = rels[i]; lpos = atomicAdd(&lc[r], 1); }
    __syncthreads();
    if (threadIdx.x < RNUM) lbase[threadIdx.x] = atomicAdd(&cur[threadIdx.x], lc[threadIdx.x]);
    __syncthreads();
    if (ok) perm[lbase[r] + lpos] = i;
}

// ---------------- stage A: y = embed[nodes] @ W_rel[r]^T + b_rel[r]  (bf16 out) ----------------
// grid: (tile upper bound, 8), block 256 (4 waves). Tile 64 rows x 64 cols, BK=32.

__launch_bounds__(256)
__global__ void k_stageA(const float* __restrict__ embed, const unsigned short* __restrict__ wrel,
                         const float* __restrict__ b_rel, const int* __restrict__ nodes,
                         const int* __restrict__ perm, const int* __restrict__ roff,
                         unsigned short* __restrict__ y) {
    __shared__ int sroff[RNUM + 1];
    if (threadIdx.x <= RNUM) sroff[threadIdx.x] = roff[threadIdx.x];
    __syncthreads();

    int tb = blockIdx.x;
    int rel = -1, row0 = 0, nrows = 0, acct = 0;
    for (int r = 0; r < RNUM; ++r) {
        int cnt = sroff[r + 1] - sroff[r];
        int tiles = (cnt + 63) >> 6;
        if (tb < acct + tiles) {
            rel = r;
            row0 = sroff[r] + (tb - acct) * 64;
            nrows = sroff[r + 1] - row0;
            if (nrows > 64) nrows = 64;
            break;
        }
        acct += tiles;
    }
    if (rel < 0) return;
    int jbase = blockIdx.y * 64;

    __shared__ __align__(16) unsigned short As[4 * 512];
    __shared__ __align__(16) unsigned short Bs[4 * 512];

    int tid = threadIdx.x;
    int lane = tid & 63;
    int wv = tid >> 6;      // wave -> col 16-group
    int quad = lane >> 4;
    int lrow = lane & 15;

    int rloc = tid >> 2;    // 0..63 : A row / B col
    int k8 = tid & 3;       // chunk within BK=32

    long node = -1;
    if (rloc < nrows) node = nodes[perm[row0 + rloc]];
    const float* arow = (node >= 0) ? (embed + node * D) : embed;
    bool avalid = (node >= 0);
    int adst = (rloc >> 4) * 512 + (k8 * 16 + (rloc & 15)) * 8;

    const unsigned short* brow = wrel + ((long)rel * D + (jbase + rloc)) * D;
    int bdst = (rloc >> 4) * 512 + (k8 * 16 + (rloc & 15)) * 8;

    f32x4_t acc[4];
#pragma unroll
    for (int m = 0; m < 4; ++m) acc[m] = (f32x4_t)(0.0f);

    for (int kb = 0; kb < D; kb += 32) {
        __syncthreads();
        {
            union { uint4 q; unsigned short u[8]; } av;
            if (avalid) {
                const float4* p = (const float4*)(arow + kb + k8 * 8);
                float4 f0 = p[0], f1 = p[1];
                av.u[0] = f2bf(f0.x); av.u[1] = f2bf(f0.y); av.u[2] = f2bf(f0.z); av.u[3] = f2bf(f0.w);
                av.u[4] = f2bf(f1.x); av.u[5] = f2bf(f1.y); av.u[6] = f2bf(f1.z); av.u[7] = f2bf(f1.w);
            } else {
                av.q.x = av.q.y = av.q.z = av.q.w = 0u;
            }
            *(uint4*)(As + adst) = av.q;
        }
        *(uint4*)(Bs + bdst) = *(const uint4*)(brow + kb + k8 * 8);
        __syncthreads();

        s16x8 bfr = *(const s16x8*)(Bs + wv * 512 + lane * 8);
#pragma unroll
        for (int m = 0; m < 4; ++m) {
            s16x8 afr = *(const s16x8*)(As + m * 512 + lane * 8);
            acc[m] = MFMA16(afr, bfr, acc[m]);
        }
    }

    int col = jbase + wv * 16 + lrow;
    float brl = b_rel[(long)rel * D + col];
#pragma unroll
    for (int m = 0; m < 4; ++m) {
#pragma unroll
        for (int rg = 0; rg < 4; ++rg) {
            int row = m * 16 + quad * 4 + rg;
            if (row < nrows) {
                int tok = perm[row0 + row];
                y[(long)tok * D + col] = f2bf(acc[m][rg] + brl);
            }
        }
    }
}

// ---------------- LSTM step: gates = [y_t | h] @ wcat^T + bias, fused nonlinearity ----------------
// grid: (ceil(bs/32), 8), block 256 (4 waves). Tile 32 rows x 64 j (x4 gates), BK=64, K=1024.

__launch_bounds__(256)
__global__ void k_step(const unsigned short* __restrict__ y,
                       const unsigned short* __restrict__ wcat,
                       const float* __restrict__ bias,
                       const unsigned short* __restrict__ h_in,
                       unsigned short* __restrict__ h_out,
                       float* __restrict__ c,
                       float* __restrict__ out,
                       int row0, int bs) {
    int rbase = blockIdx.x * 32;
    int jbase = blockIdx.y * 64;

    __shared__ __align__(16) unsigned short As[2 * 1024];    // 2 k-panels x (2 mt x 512)
    __shared__ __align__(16) unsigned short Bs[2 * 8192];    // 2 k-panels x (16 groups x 512)

    int tid = threadIdx.x;
    int lane = tid & 63;
    int wv = tid >> 6;       // wave -> j 16-group
    int quad = lane >> 4;
    int lrow = lane & 15;

    // A staging: row = tid>>3 (0..31), chunk ak8 = tid&7 (BK=64 -> 8 chunks of 8)
    int ar = tid >> 3;
    int ak8 = tid & 7;
    int adst = (ak8 >> 2) * 1024 + (ar >> 4) * 512 + ((ak8 & 3) * 16 + (ar & 15)) * 8;

    // B staging: col cc = tid: gate bg = cc>>6, jj = cc&63; 8 chunks each
    int bg = tid >> 6;
    int bjj = tid & 63;
    const unsigned short* brow = wcat + ((long)(bg * 512 + jbase + bjj)) * 1024;
    int bdst_base = (bg * 4 + (bjj >> 4)) * 512 + (bjj & 15) * 8;

    f32x4_t acc[2][4];
#pragma unroll
    for (int m = 0; m < 2; ++m)
#pragma unroll
        for (int g = 0; g < 4; ++g) acc[m][g] = (f32x4_t)(0.0f);

    int b_stage = rbase + ar;

    for (int kb = 0; kb < 1024; kb += 64) {
        __syncthreads();
        {
            uint4 v; v.x = v.y = v.z = v.w = 0u;
            if (b_stage < bs) {
                int gk = kb + ak8 * 8;
                const unsigned short* src = (gk < 512)
                    ? (y + (long)(row0 + b_stage) * 512 + gk)
                    : (h_in + (long)b_stage * 512 + (gk - 512));
                v = *(const uint4*)src;
            }
            *(uint4*)(As + adst) = v;
        }
#pragma unroll
        for (int k8 = 0; k8 < 8; ++k8) {
            int dst = (k8 >> 2) * 8192 + bdst_base + (k8 & 3) * 128;
            *(uint4*)(Bs + dst) = *(const uint4*)(brow + kb + k8 * 8);
        }
        __syncthreads();

#pragma unroll
        for (int p = 0; p < 2; ++p) {
            s16x8 a0 = *(const s16x8*)(As + p * 1024 + lane * 8);
            s16x8 a1 = *(const s16x8*)(As + p * 1024 + 512 + lane * 8);
#pragma unroll
            for (int g = 0; g < 4; ++g) {
                s16x8 bfr = *(const s16x8*)(Bs + p * 8192 + (g * 4 + wv) * 512 + lane * 8);
                acc[0][g] = MFMA16(a0, bfr, acc[0][g]);
                acc[1][g] = MFMA16(a1, bfr, acc[1][g]);
            }
        }
    }

    int j = jbase + wv * 16 + lrow;
    float bi = bias[j], bff = bias[512 + j], bgg = bias[1024 + j], boo = bias[1536 + j];
#pragma unroll
    for (int m = 0; m < 2; ++m) {
#pragma unroll
        for (int rg = 0; rg < 4; ++rg) {
            int b = rbase + m * 16 + quad * 4 + rg;
            if (b < bs) {
                float iv = acc[m][0][rg] + bi;
                float fv = acc[m][1][rg] + bff;
                float gv = acc[m][2][rg] + bgg;
                float ov = acc[m][3][rg] + boo;
                float ig = 1.0f / (1.0f + __expf(-iv));
                float fg = 1.0f / (1.0f + __expf(-fv));
                float gt = 1.0f - 2.0f / (__expf(2.0f * gv) + 1.0f);
                float og = 1.0f / (1.0f + __expf(-ov));
                long cidx = (long)b * 512 + j;
                float cn = fg * c[cidx] + ig * gt;
                float hn = og * (1.0f - 2.0f / (__expf(2.0f * cn) + 1.0f));
                c[cidx] = cn;
                out[(long)(row0 + b) * 512 + j] = hn;
                h_out[cidx] = f2bf(hn);
            }
        }
    }
}

// ---------------- host ----------------

extern "C" void kernel_launch(void* const* d_in, const int* in_sizes, int n_in,
                              void* d_out, int out_size, void* d_ws, size_t ws_size,
                              hipStream_t stream) {
    const float* embed = (const float*)d_in[0];
    const float* W_rel = (const float*)d_in[1];
    const float* b_rel = (const float*)d_in[2];
    const float* W_ih  = (const float*)d_in[3];
    const float* W_hh  = (const float*)d_in[4];
    const float* b_ih  = (const float*)d_in[5];
    const float* b_hh  = (const float*)d_in[6];
    const int* nodes = (const int*)d_in[7];
    const int* rels  = (const int*)d_in[8];
    int n_tok = in_sizes[7];
    float* out = (float*)d_out;

    char* ws = (char*)d_ws;
    size_t off = 0;
    auto alloc = [&](size_t bytes) -> void* {
        void* p = ws + off;
        off = (off + bytes + 255) & ~(size_t)255;
        return p;
    };
    unsigned short* y    = (unsigned short*)alloc((size_t)n_tok * 512 * 2);
    unsigned short* wrel = (unsigned short*)alloc((size_t)RNUM * 512 * 512 * 2);
    unsigned short* wcat = (unsigned short*)alloc((size_t)2048 * 1024 * 2);
    float* bias          = (float*)alloc(2048 * 4);
    unsigned short* h0   = (unsigned short*)alloc((size_t)1024 * 512 * 2);
    unsigned short* h1   = (unsigned short*)alloc((size_t)1024 * 512 * 2);
    float* cbuf          = (float*)alloc((size_t)1024 * 512 * 4);
    int* perm            = (int*)alloc((size_t)n_tok * 4);
    int* cnt             = (int*)alloc(64);
    int* roff            = (int*)alloc(64);
    int* cur             = (int*)alloc(64);

    hipMemsetAsync(cnt, 0, 64, stream);
    hipMemsetAsync(h0, 0, (size_t)1024 * 512 * 2, stream);
    hipMemsetAsync(cbuf, 0, (size_t)1024 * 512 * 4, stream);

    k_convert_wcat<<<dim3(2048), dim3(256), 0, stream>>>(W_ih, W_hh, b_ih, b_hh, wcat, bias);
    int nw = RNUM * 512 * 512;
    k_convert_wrel<<<dim3((nw + 255) / 256), dim3(256), 0, stream>>>(W_rel, wrel, nw);
    int nb = (n_tok + 255) / 256;
    k_count<<<dim3(nb), dim3(256), 0, stream>>>(rels, n_tok, cnt);
    k_offsets<<<dim3(1), dim3(1), 0, stream>>>(cnt, roff, cur);
    k_scatter<<<dim3(nb), dim3(256), 0, stream>>>(rels, n_tok, cur, perm);

    int tilesA = (n_tok + 63) / 64 + RNUM;  // upper bound incl. per-rel padding
    k_stageA<<<dim3(tilesA, 8), dim3(256), 0, stream>>>(embed, wrel, b_rel, nodes, perm, roff, y);

    int row0 = 0;
    unsigned short* hin = h0;
    unsigned short* hout = h1;
    for (int t = 0; t < TSTEPS; ++t) {
        int bs = 8 * (TSTEPS - t);
        if (bs > 1024) bs = 1024;
        k_step<<<dim3((bs + 31) / 32, 8), dim3(256), 0, stream>>>(y, wcat, bias, hin, hout, cbuf, out, row0, bs);
        row0 += bs;
        unsigned short* tmp = hin; hin = hout; hout = tmp;
    }
}

// Round 2
// 3953.893 us; speedup vs baseline: 1.0669x; 1.0669x over previous
//
#include <hip/hip_runtime.h>
#include <stdint.h>

#define D 512
#define RNUM 8
#define TSTEPS 128

typedef __attribute__((ext_vector_type(8))) short s16x8;
typedef __attribute__((ext_vector_type(4))) float f32x4_t;

#define MFMA16(a, b, c) __builtin_amdgcn_mfma_f32_16x16x32_bf16((a), (b), (c), 0, 0, 0)

// frag-ordered LDS linear index: mt*1024 + ks*512 + q*128 + rr*8  (16-row groups, BK=64)
#define FIDX(mt, ks, q, rr) (((mt) * 1024) + ((ks) * 512) + ((q) * 128) + ((rr) * 8))

__device__ __forceinline__ unsigned short f2bf(float f) {
    union { float f; unsigned int u; } v; v.f = f;
    unsigned int r = (v.u + 0x7FFFu + ((v.u >> 16) & 1u)) >> 16;
    return (unsigned short)r;
}
__device__ __forceinline__ float bf2f(unsigned short u) {
    union { unsigned int i; float f; } v; v.i = ((unsigned int)u) << 16;
    return v.f;
}

// ---------------- precompute ----------------

__global__ void k_convert2(const float* __restrict__ a, const float* __restrict__ b,
                           unsigned short* __restrict__ oa, unsigned short* __restrict__ ob, int n) {
    int i = blockIdx.x * 256 + threadIdx.x;
    if (i < n) { oa[i] = f2bf(a[i]); ob[i] = f2bf(b[i]); }
}

// bcomp[r][g] = b_ih[g] + b_hh[g] + sum_j W_ih[g,j] * b_rel[r,j]
__global__ void k_bcomp(const float* __restrict__ W_ih, const float* __restrict__ b_rel,
                        const float* __restrict__ b_ih, const float* __restrict__ b_hh,
                        float* __restrict__ bcomp) {
    int g = blockIdx.x;
    int t = threadIdx.x;
    __shared__ float wrow[512];
    wrow[t]       = W_ih[(long)g * 512 + t];
    wrow[t + 256] = W_ih[(long)g * 512 + t + 256];
    __syncthreads();
    int r = t >> 5, l = t & 31;
    float s = 0.0f;
    for (int j = l; j < 512; j += 32) s += wrow[j] * b_rel[r * 512 + j];
    for (int off = 16; off; off >>= 1) s += __shfl_down(s, off, 32);
    if (l == 0) bcomp[r * 2048 + g] = s + b_ih[g] + b_hh[g];
}

// wrelT[r][k][j] = bf16(W_rel[r][j][k])
__global__ void k_transpose_wrel(const float* __restrict__ W_rel, unsigned short* __restrict__ wrelT) {
    int kt = blockIdx.x, jt = blockIdx.y, r = blockIdx.z;
    int t = threadIdx.x;
    __shared__ float tile[64][65];
    for (int p = 0; p < 16; ++p) {
        int jl = p * 4 + (t >> 6);
        int kl = t & 63;
        tile[jl][kl] = W_rel[((long)r * 512 + jt * 64 + jl) * 512 + kt * 64 + kl];
    }
    __syncthreads();
    for (int p = 0; p < 16; ++p) {
        int kr = p * 4 + (t >> 6);
        int jc = t & 63;
        wrelT[((long)r * 512 + kt * 64 + kr) * 512 + jt * 64 + jc] = f2bf(tile[jc][kr]);
    }
}

__global__ void k_count(const int* __restrict__ rels, int n, int* __restrict__ cnt) {
    __shared__ int lc[RNUM];
    if (threadIdx.x < RNUM) lc[threadIdx.x] = 0;
    __syncthreads();
    int i = blockIdx.x * 256 + threadIdx.x;
    if (i < n) atomicAdd(&lc[rels[i]], 1);
    __syncthreads();
    if (threadIdx.x < RNUM) atomicAdd(&cnt[threadIdx.x], lc[threadIdx.x]);
}

__global__ void k_offsets(const int* __restrict__ cnt, int* __restrict__ roff, int* __restrict__ cur) {
    int acc = 0;
    for (int r = 0; r < RNUM; ++r) { roff[r] = acc; cur[r] = acc; acc += cnt[r]; }
    roff[RNUM] = acc;
}

__global__ void k_scatter(const int* __restrict__ rels, int n, int* __restrict__ cur, int* __restrict__ perm) {
    __shared__ int lc[RNUM];
    __shared__ int lbase[RNUM];
    if (threadIdx.x < RNUM) lc[threadIdx.x] = 0;
    __syncthreads();
    int i = blockIdx.x * 256 + threadIdx.x;
    int r = 0, lpos = 0;
    bool ok = (i < n);
    if (ok) { r = rels[i]; lpos = atomicAdd(&lc[r], 1); }
    __syncthreads();
    if (threadIdx.x < RNUM) lbase[threadIdx.x] = atomicAdd(&cur[threadIdx.x], lc[threadIdx.x]);
    __syncthreads();
    if (ok) perm[lbase[r] + lpos] = i;
}

// xg[i] = bf16(embed[nodes[perm[i]]])  (permuted order, one wave per row)
__global__ void k_gather_x(const float* __restrict__ embed, const int* __restrict__ nodes,
                           const int* __restrict__ perm, unsigned short* __restrict__ xg, int n_tok) {
    int i = blockIdx.x * 4 + (threadIdx.x >> 6);
    if (i >= n_tok) return;
    int lane = threadIdx.x & 63;
    long node = nodes[perm[i]];
    const float4* src = (const float4*)(embed + node * 512 + lane * 8);
    float4 f0 = src[0], f1 = src[1];
    union { uint4 q; unsigned short u[8]; } v;
    v.u[0] = f2bf(f0.x); v.u[1] = f2bf(f0.y); v.u[2] = f2bf(f0.z); v.u[3] = f2bf(f0.w);
    v.u[4] = f2bf(f1.x); v.u[5] = f2bf(f1.y); v.u[6] = f2bf(f1.z); v.u[7] = f2bf(f1.w);
    *(uint4*)(xg + (long)i * 512 + lane * 8) = v.q;
}

// Wc[r] = W_ih @ W_rel[r]   (2048x512 @ 512x512 -> 2048x512), NT form: B = wrelT
// tiles 64x64, BK=64, block 256 (4 waves, 2x2 wave grid)
__launch_bounds__(256)
__global__ void k_wcomp(const unsigned short* __restrict__ wih, const unsigned short* __restrict__ wrelT,
                        unsigned short* __restrict__ wc) {
    int r = blockIdx.z;
    int g0 = blockIdx.x * 64, k0 = blockIdx.y * 64;
    __shared__ __align__(16) unsigned short As[4096];
    __shared__ __align__(16) unsigned short Bs[4096];
    int t = threadIdx.x, lane = t & 63, wv = t >> 6;
    int quad = lane >> 4, lrow = lane & 15;
    int wy = wv >> 1, wx = wv & 1;

    int sr = t >> 2, sk = (t & 3) * 16;
    const unsigned short* asrc = wih + (long)(g0 + sr) * 512;
    const unsigned short* bsrc = wrelT + ((long)r * 512 + k0 + sr) * 512;
    int d0 = FIDX(sr >> 4, sk >> 5, (sk >> 3) & 3, sr & 15);

    f32x4_t acc[2][2];
#pragma unroll
    for (int i = 0; i < 2; ++i)
#pragma unroll
        for (int j = 0; j < 2; ++j) acc[i][j] = (f32x4_t)(0.0f);

    for (int kb = 0; kb < 512; kb += 64) {
        __syncthreads();
        *(uint4*)(As + d0)       = *(const uint4*)(asrc + kb + sk);
        *(uint4*)(As + d0 + 128) = *(const uint4*)(asrc + kb + sk + 8);
        *(uint4*)(Bs + d0)       = *(const uint4*)(bsrc + kb + sk);
        *(uint4*)(Bs + d0 + 128) = *(const uint4*)(bsrc + kb + sk + 8);
        __syncthreads();
#pragma unroll
        for (int ks = 0; ks < 2; ++ks) {
            s16x8 a[2], b[2];
#pragma unroll
            for (int i = 0; i < 2; ++i) a[i] = *(const s16x8*)(As + FIDX(wy * 2 + i, ks, quad, lrow));
#pragma unroll
            for (int j = 0; j < 2; ++j) b[j] = *(const s16x8*)(Bs + FIDX(wx * 2 + j, ks, quad, lrow));
#pragma unroll
            for (int i = 0; i < 2; ++i)
#pragma unroll
                for (int j = 0; j < 2; ++j) acc[i][j] = MFMA16(a[i], b[j], acc[i][j]);
        }
    }
#pragma unroll
    for (int i = 0; i < 2; ++i)
#pragma unroll
        for (int j = 0; j < 2; ++j)
#pragma unroll
            for (int rg = 0; rg < 4; ++rg) {
                int g = g0 + (wy * 2 + i) * 16 + quad * 4 + rg;
                int k = k0 + (wx * 2 + j) * 16 + lrow;
                wc[((long)r * 2048 + g) * 512 + k] = f2bf(acc[i][j][rg]);
            }
}

// gx[tok][2048] = xg[i] @ Wc[rel]^T + bcomp[rel]   (bf16 out)
// tiles 128x128, BK=64, block 256 (4 waves, 2x2 wave grid, 64x64 per wave)
__launch_bounds__(256)
__global__ void k_stageA2(const unsigned short* __restrict__ xg, const unsigned short* __restrict__ wc,
                          const float* __restrict__ bcomp, const int* __restrict__ perm,
                          const int* __restrict__ roff, unsigned short* __restrict__ gx) {
    __shared__ int sroff[RNUM + 1];
    if (threadIdx.x <= RNUM) sroff[threadIdx.x] = roff[threadIdx.x];
    __syncthreads();

    int tb = blockIdx.x;
    int rel = -1, row0 = 0, nrows = 0, acct = 0;
    for (int r = 0; r < RNUM; ++r) {
        int cnt = sroff[r + 1] - sroff[r];
        int tiles = (cnt + 127) >> 7;
        if (tb < acct + tiles) {
            rel = r;
            row0 = sroff[r] + (tb - acct) * 128;
            nrows = sroff[r + 1] - row0;
            if (nrows > 128) nrows = 128;
            break;
        }
        acct += tiles;
    }
    if (rel < 0) return;
    int jbase = blockIdx.y * 128;

    __shared__ __align__(16) unsigned short As[8192];
    __shared__ __align__(16) unsigned short Bs[8192];

    int t = threadIdx.x, lane = t & 63, wv = t >> 6;
    int quad = lane >> 4, lrow = lane & 15;
    int wy = wv >> 1, wx = wv & 1;

    int sr = t >> 1, sk = (t & 1) * 32;
    int arow = (sr < nrows) ? sr : 0;
    const unsigned short* asrc = xg + (long)(row0 + arow) * 512;
    const unsigned short* bsrc = wc + ((long)rel * 2048 + jbase + sr) * 512;
    int d0 = FIDX(sr >> 4, sk >> 5, 0, sr & 15);

    f32x4_t acc[4][4];
#pragma unroll
    for (int i = 0; i < 4; ++i)
#pragma unroll
        for (int j = 0; j < 4; ++j) acc[i][j] = (f32x4_t)(0.0f);

    for (int kb = 0; kb < 512; kb += 64) {
        __syncthreads();
#pragma unroll
        for (int q = 0; q < 4; ++q) {
            *(uint4*)(As + d0 + q * 128) = *(const uint4*)(asrc + kb + sk + q * 8);
            *(uint4*)(Bs + d0 + q * 128) = *(const uint4*)(bsrc + kb + sk + q * 8);
        }
        __syncthreads();
#pragma unroll
        for (int ks = 0; ks < 2; ++ks) {
            s16x8 a[4], b[4];
#pragma unroll
            for (int i = 0; i < 4; ++i) a[i] = *(const s16x8*)(As + FIDX(wy * 4 + i, ks, quad, lrow));
#pragma unroll
            for (int j = 0; j < 4; ++j) b[j] = *(const s16x8*)(Bs + FIDX(wx * 4 + j, ks, quad, lrow));
#pragma unroll
            for (int i = 0; i < 4; ++i)
#pragma unroll
                for (int j = 0; j < 4; ++j) acc[i][j] = MFMA16(a[i], b[j], acc[i][j]);
        }
    }

#pragma unroll
    for (int i = 0; i < 4; ++i)
#pragma unroll
        for (int rg = 0; rg < 4; ++rg) {
            int row = wy * 64 + i * 16 + quad * 4 + rg;
            if (row < nrows) {
                long tok = perm[row0 + row];
#pragma unroll
                for (int j = 0; j < 4; ++j) {
                    int col = jbase + wx * 64 + j * 16 + lrow;
                    gx[tok * 2048 + col] = f2bf(acc[i][j][rg] + bcomp[rel * 2048 + col]);
                }
            }
        }
}

// LSTM step: gates = gx_row + h @ W_hh^T, fused nonlinearity.
// tiles: BM=64 rows x BN=256 (4 gates x 64 j), BK=64, K=512. block 256 (4 waves; wave = j 16-group).
__launch_bounds__(256)
__global__ void k_step2(const unsigned short* __restrict__ gx,
                        const unsigned short* __restrict__ whh,
                        const unsigned short* __restrict__ h_in,
                        unsigned short* __restrict__ h_out,
                        float* __restrict__ c,
                        float* __restrict__ out,
                        int row0, int bs) {
    int rbase = blockIdx.x * 64;
    int jbase = blockIdx.y * 64;

    __shared__ __align__(16) unsigned short As[4096];    // 64 rows x 64 k
    __shared__ __align__(16) unsigned short Bs[16384];   // 256 cols x 64 k

    int t = threadIdx.x, lane = t & 63, wv = t >> 6;
    int quad = lane >> 4, lrow = lane & 15;

    // A staging: r = t>>2, 16 elems at (t&3)*16
    int sr = t >> 2, sk = (t & 3) * 16;
    int da = FIDX(sr >> 4, sk >> 5, (sk >> 3) & 3, sr & 15);
    bool avalid = (rbase + sr) < bs;
    const unsigned short* asrc = h_in + (long)(rbase + sr) * 512;

    // B staging: col c = t (gate = t>>6, jj = t&63), 8 chunks of 8
    int bn = t >> 4, brr = t & 15;
    const unsigned short* bsrc = whh + ((long)((t >> 6) * 512 + jbase + (t & 63))) * 512;
    int db = bn * 1024 + brr * 8;

    f32x4_t acc[4][4];   // [mt][gate]
#pragma unroll
    for (int m = 0; m < 4; ++m)
#pragma unroll
        for (int g = 0; g < 4; ++g) acc[m][g] = (f32x4_t)(0.0f);

    for (int kb = 0; kb < 512; kb += 64) {
        __syncthreads();
        {
            uint4 v0, v1;
            v0.x = v0.y = v0.z = v0.w = 0u;
            v1 = v0;
            if (avalid) {
                v0 = *(const uint4*)(asrc + kb + sk);
                v1 = *(const uint4*)(asrc + kb + sk + 8);
            }
            *(uint4*)(As + da) = v0;
            *(uint4*)(As + da + 128) = v1;
        }
#pragma unroll
        for (int m = 0; m < 8; ++m) {
            *(uint4*)(Bs + db + m * 128) = *(const uint4*)(bsrc + kb + m * 8);
        }
        __syncthreads();

#pragma unroll
        for (int ks = 0; ks < 2; ++ks) {
            s16x8 a[4];
#pragma unroll
            for (int m = 0; m < 4; ++m) a[m] = *(const s16x8*)(As + FIDX(m, ks, quad, lrow));
#pragma unroll
            for (int g = 0; g < 4; ++g) {
                s16x8 b = *(const s16x8*)(Bs + (g * 4 + wv) * 1024 + ks * 512 + quad * 128 + lrow * 8);
#pragma unroll
                for (int m = 0; m < 4; ++m) acc[m][g] = MFMA16(a[m], b, acc[m][g]);
            }
        }
    }

    int j = jbase + wv * 16 + lrow;
#pragma unroll
    for (int m = 0; m < 4; ++m) {
#pragma unroll
        for (int rg = 0; rg < 4; ++rg) {
            int b = rbase + m * 16 + quad * 4 + rg;
            if (b < bs) {
                long gbase = (long)(row0 + b) * 2048;
                float iv = acc[m][0][rg] + bf2f(gx[gbase + j]);
                float fv = acc[m][1][rg] + bf2f(gx[gbase + 512 + j]);
                float gv = acc[m][2][rg] + bf2f(gx[gbase + 1024 + j]);
                float ov = acc[m][3][rg] + bf2f(gx[gbase + 1536 + j]);
                float ig = 1.0f / (1.0f + __expf(-iv));
                float fg = 1.0f / (1.0f + __expf(-fv));
                float gt = 1.0f - 2.0f / (__expf(2.0f * gv) + 1.0f);
                float og = 1.0f / (1.0f + __expf(-ov));
                long cidx = (long)b * 512 + j;
                float cn = fg * c[cidx] + ig * gt;
                float hn = og * (1.0f - 2.0f / (__expf(2.0f * cn) + 1.0f));
                c[cidx] = cn;
                out[(long)(row0 + b) * 512 + j] = hn;
                h_out[cidx] = f2bf(hn);
            }
        }
    }
}

// ---------------- host ----------------

extern "C" void kernel_launch(void* const* d_in, const int* in_sizes, int n_in,
                              void* d_out, int out_size, void* d_ws, size_t ws_size,
                              hipStream_t stream) {
    const float* embed = (const float*)d_in[0];
    const float* W_rel = (const float*)d_in[1];
    const float* b_rel = (const float*)d_in[2];
    const float* W_ih  = (const float*)d_in[3];
    const float* W_hh  = (const float*)d_in[4];
    const float* b_ih  = (const float*)d_in[5];
    const float* b_hh  = (const float*)d_in[6];
    const int* nodes = (const int*)d_in[7];
    const int* rels  = (const int*)d_in[8];
    int n_tok = in_sizes[7];
    float* out = (float*)d_out;

    char* ws = (char*)d_ws;
    size_t off = 0;
    auto alloc = [&](size_t bytes) -> void* {
        void* p = ws + off;
        off = (off + bytes + 255) & ~(size_t)255;
        return p;
    };
    unsigned short* gx    = (unsigned short*)alloc((size_t)n_tok * 2048 * 2);
    unsigned short* xg    = (unsigned short*)alloc((size_t)n_tok * 512 * 2);
    unsigned short* wih   = (unsigned short*)alloc((size_t)2048 * 512 * 2);
    unsigned short* whh   = (unsigned short*)alloc((size_t)2048 * 512 * 2);
    unsigned short* wrelT = (unsigned short*)alloc((size_t)RNUM * 512 * 512 * 2);
    unsigned short* wc    = (unsigned short*)alloc((size_t)RNUM * 2048 * 512 * 2);
    float* bcomp          = (float*)alloc((size_t)RNUM * 2048 * 4);
    unsigned short* h0    = (unsigned short*)alloc((size_t)1024 * 512 * 2);
    unsigned short* h1    = (unsigned short*)alloc((size_t)1024 * 512 * 2);
    float* cbuf           = (float*)alloc((size_t)1024 * 512 * 4);
    int* perm             = (int*)alloc((size_t)n_tok * 4);
    int* cnt              = (int*)alloc(64);
    int* roff             = (int*)alloc(64);
    int* cur              = (int*)alloc(64);

    if (off > ws_size) return;  // workspace too small: fail loudly (out stays poisoned)

    hipMemsetAsync(cnt, 0, 64, stream);
    hipMemsetAsync(h0, 0, (size_t)1024 * 512 * 2, stream);
    hipMemsetAsync(cbuf, 0, (size_t)1024 * 512 * 4, stream);

    int nw = 2048 * 512;
    k_convert2<<<dim3((nw + 255) / 256), dim3(256), 0, stream>>>(W_ih, W_hh, wih, whh, nw);
    k_bcomp<<<dim3(2048), dim3(256), 0, stream>>>(W_ih, b_rel, b_ih, b_hh, bcomp);
    k_transpose_wrel<<<dim3(8, 8, 8), dim3(256), 0, stream>>>(W_rel, wrelT);

    int nb = (n_tok + 255) / 256;
    k_count<<<dim3(nb), dim3(256), 0, stream>>>(rels, n_tok, cnt);
    k_offsets<<<dim3(1), dim3(1), 0, stream>>>(cnt, roff, cur);
    k_scatter<<<dim3(nb), dim3(256), 0, stream>>>(rels, n_tok, cur, perm);

    k_gather_x<<<dim3((n_tok + 3) / 4), dim3(256), 0, stream>>>(embed, nodes, perm, xg, n_tok);
    k_wcomp<<<dim3(32, 8, 8), dim3(256), 0, stream>>>(wih, wrelT, wc);

    int tilesA = (n_tok + 127) / 128 + RNUM;
    k_stageA2<<<dim3(tilesA, 16), dim3(256), 0, stream>>>(xg, wc, bcomp, perm, roff, gx);

    int row0 = 0;
    unsigned short* hin = h0;
    unsigned short* hout = h1;
    for (int tt = 0; tt < TSTEPS; ++tt) {
        int bs = 8 * (TSTEPS - tt);
        if (bs > 1024) bs = 1024;
        k_step2<<<dim3((bs + 63) / 64, 8), dim3(256), 0, stream>>>(gx, whh, hin, hout, cbuf, out, row0, bs);
        row0 += bs;
        unsigned short* tmp = hin; hin = hout; hout = tmp;
    }
}